// Round 10
// baseline (325.423 us; speedup 1.0000x reference)
//
#include <hip/hip_runtime.h>

#define TOK 4096
#define HID 1024
#define NEXP 8
#define CAP 512
#define WSZ 1048576  // HID*HID

typedef _Float16 f16;
typedef f16 f16x8 __attribute__((ext_vector_type(8)));
typedef f16 f16x4 __attribute__((ext_vector_type(4)));
typedef f16 f16x2 __attribute__((ext_vector_type(2)));
typedef float f32x4 __attribute__((ext_vector_type(4)));

typedef const __attribute__((address_space(1))) void gvoid;
typedef __attribute__((address_space(3))) void lvoid;

__device__ __forceinline__ void gld16(const void* g, void* l) {
  __builtin_amdgcn_global_load_lds((gvoid*)g, (lvoid*)l, 16, 0, 0);
}

// ---------------------------------------------------------------------------
// Fused GEMM + weight-transpose + gate(+scan) kernel.
// Blocks [0, nGemm): MFMA f16 GEMM tile 128x128, BK=64, 8 waves, wave-tile
//   64x32, bijective XCD swizzle, counted-vmcnt 2-phase pipeline (round-8).
// Blocks [nGemm, nGemm+nTrans): transpose-cast of weight matrices.
// Blocks [nGemm+nTrans, +nGate): gate via combined weight G (logits =
//   gX@G + Gb), 16 tokens/block (32 lanes each); the LAST gate block to
//   finish (threadfence+atomic counter) also runs the capacity scan and
//   writes rowmap. Gate inputs are ready BEFORE this dispatch -> gate/scan
//   cost hides under the GEMM.
// MODE 0: C[r][col] = v ; MODE 1: A gathered via rowmap (-1 -> zero row TOK);
// MODE 2: C[rowmap[r]][col] = v * gmax[rowmap[r]] (skip rowmap=-1)
// ---------------------------------------------------------------------------
template<int MODE>
__global__ __launch_bounds__(512, 1) void gemm_fused(
    const f16* __restrict__ A, const f16* __restrict__ Bt,
    const float* __restrict__ bias, f16* __restrict__ C,
    const int* __restrict__ rowmap, const float* __restrict__ gmax,
    int rowsPerExpert, long bStride, int biasStride,
    const float* __restrict__ tsrc, f16* __restrict__ tdst,
    const f16* __restrict__ gX, const float* __restrict__ G,
    const float* __restrict__ Gb, int* __restrict__ gidx,
    float* __restrict__ ggmax, int* __restrict__ grm,
    int* __restrict__ counter, int nGemm, int nTrans, int nGate)
{
  __shared__ __align__(16) unsigned char smem[65536];
  const int tid = threadIdx.x;

  if ((int)blockIdx.x >= nGemm + nTrans) {
    // ---------------- gate role (+ scan in last block) ----------------
    const int gb = blockIdx.x - nGemm - nTrans;   // 0..nGate-1
    const int tok = gb * 16 + (tid >> 5);
    const int sl = tid & 31;
    const f16* row = gX + (size_t)tok * HID + sl * 32;
    float xv[32];
    #pragma unroll
    for (int v = 0; v < 4; ++v) {
      f16x8 hv = *(const f16x8*)(row + v * 8);
      #pragma unroll
      for (int j = 0; j < 8; ++j) xv[v * 8 + j] = (float)hv[j];
    }
    float p[NEXP];
    #pragma unroll
    for (int e = 0; e < NEXP; ++e) p[e] = 0.f;
    const float4* g4 = (const float4*)(G + (size_t)(sl * 32) * NEXP);
    #pragma unroll
    for (int j = 0; j < 32; ++j) {
      float4 lo = g4[2 * j], hi = g4[2 * j + 1];
      p[0] += xv[j] * lo.x; p[1] += xv[j] * lo.y;
      p[2] += xv[j] * lo.z; p[3] += xv[j] * lo.w;
      p[4] += xv[j] * hi.x; p[5] += xv[j] * hi.y;
      p[6] += xv[j] * hi.z; p[7] += xv[j] * hi.w;
    }
    #pragma unroll
    for (int m = 1; m < 32; m <<= 1) {
      #pragma unroll
      for (int e = 0; e < NEXP; ++e) p[e] += __shfl_xor(p[e], m, 64);
    }
    if (sl == 0) {
      #pragma unroll
      for (int e = 0; e < NEXP; ++e) p[e] += Gb[e];
      float mx = p[0]; int am = 0;
      #pragma unroll
      for (int e = 1; e < NEXP; ++e)
        if (p[e] > mx) { mx = p[e]; am = e; }
      float s = 0.f;
      #pragma unroll
      for (int e = 0; e < NEXP; ++e) s += expf(p[e] - mx);
      gidx[tok] = am;
      ggmax[tok] = 1.f / s;
    }
    // last-block-runs-scan (threadFenceReduction pattern)
    __threadfence();
    __syncthreads();
    int* sflag = (int*)(smem + 32768);
    if (tid == 0) sflag[0] = (atomicAdd(counter, 1) == nGate - 1) ? 1 : 0;
    __syncthreads();
    if (!sflag[0]) return;
    __threadfence();
    int* sidx = (int*)smem;
    for (int i = tid; i < TOK; i += 512) sidx[i] = gidx[i];
    for (int i = tid; i < NEXP * CAP; i += 512) grm[i] = -1;
    __syncthreads();
    const int wave = tid >> 6, lane = tid & 63;
    int running = 0;
    for (int ch = 0; ch < TOK / 64; ++ch) {
      int t = ch * 64 + lane;
      bool flag = (sidx[t] == wave);
      unsigned long long m = __ballot(flag);
      int pos = running + __popcll(m & ((1ull << lane) - 1ull));
      if (flag && pos < CAP) grm[wave * CAP + pos] = t;
      running += __popcll(m);
    }
    return;
  }

  if ((int)blockIdx.x >= nGemm) {
    // ---------------- transpose-cast role ----------------
    float (*t)[65] = (float (*)[65])smem;   // [128][65] f32
    const int tb = blockIdx.x - nGemm;
    const int mat = tb >> 7, t7 = tb & 127;
    const int nb = (t7 & 7) * 128, kb = (t7 >> 3) * 64;
    const float* src = tsrc + (size_t)mat * WSZ;
    f16* d = tdst + (size_t)mat * WSZ;
    const int half = tid >> 8, tl = tid & 255;
    const int rr = tl >> 4, c4 = (tl & 15) * 4;
    float (*th)[65] = t + half * 64;
    float4 v[4];
    #pragma unroll
    for (int p = 0; p < 4; ++p)
      v[p] = *(const float4*)&src[(size_t)(kb + p * 16 + rr) * HID + nb + half * 64 + c4];
    #pragma unroll
    for (int p = 0; p < 4; ++p) {
      th[p * 16 + rr][c4 + 0] = v[p].x;
      th[p * 16 + rr][c4 + 1] = v[p].y;
      th[p * 16 + rr][c4 + 2] = v[p].z;
      th[p * 16 + rr][c4 + 3] = v[p].w;
    }
    __syncthreads();
    #pragma unroll
    for (int it = 0; it < 2; ++it) {
      const int p = it * 256 + tl;
      const int n = p >> 3, kc = p & 7;
      f16x8 o;
      #pragma unroll
      for (int j = 0; j < 8; ++j) o[j] = (f16)th[kc * 8 + j][n];
      *(f16x8*)&d[(size_t)(nb + half * 64 + n) * HID + kb + kc * 8] = o;
    }
    return;
  }

  // ---------------- GEMM role ----------------
  f16* As0 = (f16*)smem;             // [2][128*64] f16
  f16* Bs0 = (f16*)(smem + 32768);   // [2][128*64] f16
  const int w = tid >> 6, l = tid & 63;
  const int wr = w >> 2, wc = w & 3;

  const int orig = blockIdx.x;                 // 0..255
  const int sw = (orig & 7) * 32 + (orig >> 3);
  const int bx = sw & 7, by = sw >> 3;
  const int e = (by * 128) / rowsPerExpert;

  const int lr = l >> 3;
  const int chunkSw = ((l & 7) ^ lr) * 8;

  const f16* pst[4];
  if (w < 4) {
    #pragma unroll
    for (int i = 0; i < 4; ++i) {
      int r = by * 128 + w * 32 + i * 8 + lr;
      long tok = r;
      if (MODE == 1) { int t = rowmap[r]; tok = (t < 0) ? (long)TOK : (long)t; }
      pst[i] = A + tok * HID + chunkSw;
    }
  } else {
    #pragma unroll
    for (int i = 0; i < 4; ++i)
      pst[i] = Bt + (size_t)e * bStride
             + (size_t)(bx * 128 + (w - 4) * 32 + i * 8 + lr) * HID + chunkSw;
  }

  f32x4 acc[4][2];
  #pragma unroll
  for (int i = 0; i < 4; ++i)
    #pragma unroll
    for (int j = 0; j < 2; ++j) acc[i][j] = (f32x4){0.f, 0.f, 0.f, 0.f};

  const int g = l >> 4, c = l & 15, sa = c & 7;

  {
    f16* db = (w < 4) ? As0 + (w * 32) * 64 : Bs0 + ((w - 4) * 32) * 64;
    #pragma unroll
    for (int i = 0; i < 4; ++i) gld16(pst[i], db + i * 8 * 64);
  }

  int cur = 0;
  for (int t = 0; t < 15; ++t) {
    {
      const int k0 = (t + 1) * 64;
      f16* db = (w < 4) ? As0 + ((cur ^ 1) * 8192) + (w * 32) * 64
                        : Bs0 + ((cur ^ 1) * 8192) + ((w - 4) * 32) * 64;
      #pragma unroll
      for (int i = 0; i < 4; ++i) gld16(pst[i] + k0, db + i * 8 * 64);
    }
    asm volatile("s_waitcnt vmcnt(4)" ::: "memory");
    asm volatile("s_barrier" ::: "memory");
    __builtin_amdgcn_s_setprio(1);
    #pragma unroll
    for (int h = 0; h < 2; ++h) {
      const int q = ((h * 4 + g) ^ sa) * 8;
      f16x8 af[4], bf[2];
      #pragma unroll
      for (int mi = 0; mi < 4; ++mi)
        af[mi] = *(const f16x8*)&As0[cur * 8192 + (wr * 64 + mi * 16 + c) * 64 + q];
      #pragma unroll
      for (int ni = 0; ni < 2; ++ni)
        bf[ni] = *(const f16x8*)&Bs0[cur * 8192 + (wc * 32 + ni * 16 + c) * 64 + q];
      #pragma unroll
      for (int mi = 0; mi < 4; ++mi)
        #pragma unroll
        for (int ni = 0; ni < 2; ++ni)
          acc[mi][ni] = __builtin_amdgcn_mfma_f32_16x16x32_f16(
              af[mi], bf[ni], acc[mi][ni], 0, 0, 0);
    }
    __builtin_amdgcn_s_setprio(0);
    asm volatile("s_barrier" ::: "memory");
    cur ^= 1;
  }
  asm volatile("s_waitcnt vmcnt(0)" ::: "memory");
  asm volatile("s_barrier" ::: "memory");
  __builtin_amdgcn_s_setprio(1);
  #pragma unroll
  for (int h = 0; h < 2; ++h) {
    const int q = ((h * 4 + g) ^ sa) * 8;
    f16x8 af[4], bf[2];
    #pragma unroll
    for (int mi = 0; mi < 4; ++mi)
      af[mi] = *(const f16x8*)&As0[cur * 8192 + (wr * 64 + mi * 16 + c) * 64 + q];
    #pragma unroll
    for (int ni = 0; ni < 2; ++ni)
      bf[ni] = *(const f16x8*)&Bs0[cur * 8192 + (wc * 32 + ni * 16 + c) * 64 + q];
    #pragma unroll
    for (int mi = 0; mi < 4; ++mi)
      #pragma unroll
      for (int ni = 0; ni < 2; ++ni)
        acc[mi][ni] = __builtin_amdgcn_mfma_f32_16x16x32_f16(
            af[mi], bf[ni], acc[mi][ni], 0, 0, 0);
  }
  __builtin_amdgcn_s_setprio(0);

  int tk[4][4];
  float gv[4][4];
  if (MODE == 2) {
    #pragma unroll
    for (int mi = 0; mi < 4; ++mi)
      #pragma unroll
      for (int rr = 0; rr < 4; ++rr) {
        int r = by * 128 + wr * 64 + mi * 16 + g * 4 + rr;
        int t = rowmap[r];
        tk[mi][rr] = t;
        gv[mi][rr] = (t >= 0) ? gmax[t] : 0.f;
      }
  }
  #pragma unroll
  for (int ni = 0; ni < 2; ++ni) {
    const int col = bx * 128 + wc * 32 + ni * 16 + c;
    const float bv = bias[(size_t)e * biasStride + col];
    #pragma unroll
    for (int mi = 0; mi < 4; ++mi) {
      #pragma unroll
      for (int rr = 0; rr < 4; ++rr) {
        const float v = acc[mi][ni][rr] + bv;
        if (MODE == 2) {
          if (tk[mi][rr] >= 0)
            C[(size_t)tk[mi][rr] * HID + col] = (f16)(v * gv[mi][rr]);
        } else {
          const int row = by * 128 + wr * 64 + mi * 16 + g * 4 + rr;
          C[(size_t)row * HID + col] = (f16)v;
        }
      }
    }
  }
}

// ---------------------------------------------------------------------------
// prep2:
//  blocks [0,2048):   cast x f32->f16, zero C1/C2 + pad rows; block 0 zeroes
//                     the gate counters.
//  blocks [2048,2816): transpose-cast w1,w2,w3 (64x64 tiles).
//  blocks [2816,2880): combined gate weights G1 = w1@wg1, G2 = w2@wg2
//                     ([1024][8] f32); kb==0 blocks also compute
//                     Gb = b@wg ([8] f32).
// ---------------------------------------------------------------------------
__global__ __launch_bounds__(256) void prep2(
    const float* __restrict__ x, f16* __restrict__ X0,
    f16* __restrict__ c1, f16* __restrict__ c2,
    f16* __restrict__ p1, f16* __restrict__ p2,
    const float* __restrict__ w1, const float* __restrict__ w2,
    const float* __restrict__ w3, f16* __restrict__ WT,
    const float* __restrict__ wg1, const float* __restrict__ wg2,
    const float* __restrict__ b1, const float* __restrict__ b2,
    float* __restrict__ G1, float* __restrict__ G2,
    float* __restrict__ Gb1, float* __restrict__ Gb2,
    int* __restrict__ counters)
{
  __shared__ float sh[8192];   // 32 KB
  const int tid = threadIdx.x;
  if ((int)blockIdx.x < 2048) {
    if (blockIdx.x == 0 && tid < 2) counters[tid] = 0;
    const f16x8 zz = {0, 0, 0, 0, 0, 0, 0, 0};
    #pragma unroll
    for (int it = 0; it < 2; ++it) {
      const size_t i = (size_t)blockIdx.x * 256 + tid + (size_t)it * 524288;
      float4 v = *(const float4*)&x[i * 4];
      f16x4 o = {(f16)v.x, (f16)v.y, (f16)v.z, (f16)v.w};
      *(f16x4*)&X0[i * 4] = o;
      if (i < 524288) { ((f16x8*)c1)[i] = zz; ((f16x8*)c2)[i] = zz; }
      if (i < 128)    { ((f16x8*)p1)[i] = zz; ((f16x8*)p2)[i] = zz; }
    }
    return;
  }
  if ((int)blockIdx.x < 2816) {
    const int zb = blockIdx.x - 2048;
    const int z = zb >> 8, t7 = zb & 255;
    const float* src = (z == 0) ? w1 : (z == 1) ? w2 : w3;
    f16* d = WT + (size_t)z * WSZ;
    const int kb = (t7 >> 4) * 64, nb = (t7 & 15) * 64;
    const int rr = tid >> 4, c4 = (tid & 15) * 4;
    float4 v[4];
    #pragma unroll
    for (int p = 0; p < 4; ++p)
      v[p] = *(const float4*)&src[(size_t)(kb + p * 16 + rr) * HID + nb + c4];
    #pragma unroll
    for (int p = 0; p < 4; ++p) {
      sh[(p * 16 + rr) * 65 + c4 + 0] = v[p].x;
      sh[(p * 16 + rr) * 65 + c4 + 1] = v[p].y;
      sh[(p * 16 + rr) * 65 + c4 + 2] = v[p].z;
      sh[(p * 16 + rr) * 65 + c4 + 3] = v[p].w;
    }
    __syncthreads();
    #pragma unroll
    for (int half = 0; half < 2; ++half) {
      const int p = half * 256 + tid;
      const int n = p >> 3, kc = p & 7;
      f16x8 o;
      #pragma unroll
      for (int j = 0; j < 8; ++j) o[j] = (f16)sh[(kc * 8 + j) * 65 + n];
      *(f16x8*)&d[(size_t)(nb + n) * HID + kb + kc * 8] = o;
    }
    return;
  }
  // ---- combined gate weight role ----
  const int gz = blockIdx.x - 2816;
  const int which = gz >> 5;                 // 0: layer1, 1: layer2
  const int kb = (gz & 31) * 32;
  const float* w  = which ? w2 : w1;
  const float* wg = which ? wg2 : wg1;
  const float* b  = which ? b2 : b1;
  float* Gout  = which ? G2 : G1;
  float* GbOut = which ? Gb2 : Gb1;
  for (int i = tid; i < 8192; i += 256) sh[i] = wg[i];
  __syncthreads();
  const int k = kb + (tid >> 3), ee = tid & 7;
  const float4* wrow = (const float4*)(w + (size_t)k * HID);
  float acc = 0.f;
  for (int m4 = 0; m4 < 256; ++m4) {
    float4 wv = wrow[m4];
    acc += wv.x * sh[(m4 * 4 + 0) * 8 + ee] + wv.y * sh[(m4 * 4 + 1) * 8 + ee]
         + wv.z * sh[(m4 * 4 + 2) * 8 + ee] + wv.w * sh[(m4 * 4 + 3) * 8 + ee];
  }
  Gout[k * 8 + ee] = acc;
  if (kb == 0 && tid < 8) {
    float s = 0.f;
    for (int m = 0; m < HID; ++m) s += b[m] * sh[m * 8 + tid];
    GbOut[tid] = s;
  }
}

// ---------------------------------------------------------------------------
// meanHC: partial sums over 32-s chunks of H and C2.  grid (2,8,16).
// ---------------------------------------------------------------------------
__global__ __launch_bounds__(256) void meanHC_kernel(
    const f16* __restrict__ Hb, const f16* __restrict__ C2b,
    float* __restrict__ pH, float* __restrict__ pC)
{
  const int h2 = blockIdx.x * 256 + threadIdx.x;  // 0..511
  const int b = blockIdx.y, sc = blockIdx.z;
  const f16x2* pa = (const f16x2*)(Hb + ((size_t)b * 512 + sc * 32) * HID) + h2;
  const f16x2* pc = (const f16x2*)(C2b + ((size_t)b * 512 + sc * 32) * HID) + h2;
  float a0 = 0.f, a1 = 0.f, c0 = 0.f, c1 = 0.f;
  #pragma unroll 4
  for (int s = 0; s < 32; ++s) {
    f16x2 va = pa[(size_t)s * 512];
    f16x2 vc = pc[(size_t)s * 512];
    a0 += (float)va[0]; a1 += (float)va[1];
    c0 += (float)vc[0]; c1 += (float)vc[1];
  }
  float* oh = pH + ((size_t)sc * 8 + b) * HID;
  float* oc = pC + ((size_t)sc * 8 + b) * HID;
  oh[h2 * 2] = a0; oh[h2 * 2 + 1] = a1;
  oc[h2 * 2] = c0; oc[h2 * 2 + 1] = c1;
}

// ---------------------------------------------------------------------------
// sent[b][col] = mean_s H + b3[col] + (mean_s C2) @ w3   (exact commute).
// ---------------------------------------------------------------------------
__global__ __launch_bounds__(256) void sent_kernel(
    const float* __restrict__ pH, const float* __restrict__ pC,
    const f16* __restrict__ WT2, const float* __restrict__ b3,
    float* __restrict__ sent)
{
  __shared__ float c2m[HID];
  const int tid = threadIdx.x;
  const int b = blockIdx.x >> 2, ch = blockIdx.x & 3;
  for (int kk = tid; kk < HID; kk += 256) {
    float s = 0.f;
    #pragma unroll
    for (int sc = 0; sc < 16; ++sc) s += pC[((size_t)sc * 8 + b) * HID + kk];
    c2m[kk] = s * (1.f / 512.f);
  }
  __syncthreads();
  const int col = ch * 256 + tid;
  float hv = 0.f;
  #pragma unroll
  for (int sc = 0; sc < 16; ++sc) hv += pH[((size_t)sc * 8 + b) * HID + col];
  float acc = hv * (1.f / 512.f) + b3[col];
  const f16* wrow = WT2 + (size_t)col * HID;
  for (int k0 = 0; k0 < HID; k0 += 8) {
    f16x8 wv = *(const f16x8*)(wrow + k0);
    #pragma unroll
    for (int j = 0; j < 8; ++j) acc += c2m[k0 + j] * (float)wv[j];
  }
  sent[b * HID + col] = acc;
}

// ---------------------------------------------------------------------------
__global__ __launch_bounds__(1024) void loss_kernel(
    const float* __restrict__ sent, const int* __restrict__ y,
    float* __restrict__ out)
{
  __shared__ float red[17];
  const int tid = threadIdx.x;
  const int wid = tid >> 6, lane = tid & 63;
  float loss = 0.0f;
  for (int b = 0; b < 8; ++b) {
    const float v = sent[b * HID + tid];
    float m = v;
    #pragma unroll
    for (int o = 32; o; o >>= 1) m = fmaxf(m, __shfl_xor(m, o, 64));
    if (lane == 0) red[wid] = m;
    __syncthreads();
    if (tid < 16) {
      float mm = red[tid];
      #pragma unroll
      for (int o = 8; o; o >>= 1) mm = fmaxf(mm, __shfl_xor(mm, o, 16));
      if (tid == 0) red[16] = mm;
    }
    __syncthreads();
    const float M = red[16];
    float s = expf(v - M);
    #pragma unroll
    for (int o = 32; o; o >>= 1) s += __shfl_xor(s, o, 64);
    __syncthreads();
    if (lane == 0) red[wid] = s;
    __syncthreads();
    if (tid < 16) {
      float ss = red[tid];
      #pragma unroll
      for (int o = 8; o; o >>= 1) ss += __shfl_xor(ss, o, 16);
      if (tid == 0) red[16] = M + logf(ss);
    }
    __syncthreads();
    if (tid == 0) loss += -(sent[b * HID + y[b]] - red[16]);
    __syncthreads();
  }
  if (tid == 0) out[0] = loss * (1.0f / 8.0f);
}

// ---------------------------------------------------------------------------
extern "C" void kernel_launch(void* const* d_in, const int* in_sizes, int n_in,
                              void* d_out, int out_size, void* d_ws, size_t ws_size,
                              hipStream_t stream)
{
  const float* x    = (const float*)d_in[0];
  const int*   y    = (const int*)d_in[1];
  const float* w1   = (const float*)d_in[2];
  const float* b1   = (const float*)d_in[3];
  const float* w2   = (const float*)d_in[4];
  const float* b2   = (const float*)d_in[5];
  const float* w3   = (const float*)d_in[6];
  const float* b3   = (const float*)d_in[7];
  const float* wg1  = (const float*)d_in[8];
  const float* e1w1 = (const float*)d_in[9];
  const float* e1b1 = (const float*)d_in[10];
  const float* e1w2 = (const float*)d_in[11];
  const float* e1b2 = (const float*)d_in[12];
  const float* wg2  = (const float*)d_in[13];
  const float* e2w1 = (const float*)d_in[14];
  const float* e2b1 = (const float*)d_in[15];
  const float* e2w2 = (const float*)d_in[16];
  const float* e2b2 = (const float*)d_in[17];

  // workspace (~137 MB)
  f16* WT = (f16*)d_ws;                          // 35 x [1024][1024] f16
  f16* X0 = WT + (size_t)35 * WSZ;               // [4096][1024]
  f16* H  = X0 + (size_t)TOK * HID;              // [4097][1024] (pad row)
  f16* EA = H + (size_t)(TOK + 1) * HID;         // [4096][1024]
  f16* C1 = EA + (size_t)TOK * HID;              // [4096][1024]
  f16* M1 = C1 + (size_t)TOK * HID;              // [4097][1024] (pad row)
  f16* C2 = M1 + (size_t)(TOK + 1) * HID;        // [4096][1024]
  float* gmax1 = (float*)(C2 + (size_t)TOK * HID);
  float* gmax2 = gmax1 + TOK;
  int* idx1    = (int*)(gmax2 + TOK);
  int* idx2    = idx1 + TOK;
  int* rm1     = idx2 + TOK;
  int* rm2     = rm1 + NEXP * CAP;
  int* counters = rm2 + NEXP * CAP;              // [2]
  float* G1    = (float*)(counters + 16);        // [1024][8]
  float* G2    = G1 + HID * NEXP;
  float* Gb1   = G2 + HID * NEXP;                // [8]
  float* Gb2   = Gb1 + 8;
  float* sent  = Gb2 + 8;
  float* pH    = sent + 8 * HID;                 // [16][8][1024]
  float* pC    = pH + 16 * 8 * HID;              // [16][8][1024]

  f16* WTe1a = WT + (size_t)3 * WSZ;
  f16* WTe1b = WT + (size_t)11 * WSZ;
  f16* WTe2a = WT + (size_t)19 * WSZ;
  f16* WTe2b = WT + (size_t)27 * WSZ;

  // prep: x cast + zeros + w1/w2/w3 transposes + combined gate weights
  prep2<<<2880, 256, 0, stream>>>(x, X0, C1, C2,
                                  H + (size_t)TOK * HID, M1 + (size_t)TOK * HID,
                                  w1, w2, w3, WT, wg1, wg2, b1, b2,
                                  G1, G2, Gb1, Gb2, counters);

  // g1: H = X0 @ w1^T + b1  (+ transpose e1w1) (+ gate1 from X0 -> rm1)
  gemm_fused<0><<<256 + 1024 + 256, 512, 0, stream>>>(
      X0, WT, b1, H, nullptr, nullptr, TOK, 0, 0,
      e1w1, WTe1a, X0, G1, Gb1, idx1, gmax1, rm1, counters + 0,
      256, 1024, 256);

  // g2: EA = gather(H) @ e1w1^T + e1b1  (+ transpose e1w2)
  gemm_fused<1><<<256 + 1024, 512, 0, stream>>>(
      H, WTe1a, e1b1, EA, rm1, nullptr, CAP, WSZ, HID,
      e1w2, WTe1b, nullptr, nullptr, nullptr, nullptr, nullptr, nullptr, nullptr,
      256, 1024, 0);

  // g3: C1 = scatter(EA @ e1w2^T + e1b2) * gmax1  (+ transpose e2w1)
  gemm_fused<2><<<256 + 1024, 512, 0, stream>>>(
      EA, WTe1b, e1b2, C1, rm1, gmax1, CAP, WSZ, HID,
      e2w1, WTe2a, nullptr, nullptr, nullptr, nullptr, nullptr, nullptr, nullptr,
      256, 1024, 0);

  // g4: M1 = C1 @ w2^T + b2  (+ transpose e2w2) (+ gate2 from C1 -> rm2)
  gemm_fused<0><<<256 + 1024 + 256, 512, 0, stream>>>(
      C1, WT + (size_t)1 * WSZ, b2, M1, nullptr, nullptr, TOK, 0, 0,
      e2w2, WTe2b, C1, G2, Gb2, idx2, gmax2, rm2, counters + 1,
      256, 1024, 256);

  // g5: EA = gather(M1) @ e2w1^T + e2b1
  gemm_fused<1><<<256, 512, 0, stream>>>(
      M1, WTe2a, e2b1, EA, rm2, nullptr, CAP, WSZ, HID,
      nullptr, nullptr, nullptr, nullptr, nullptr, nullptr, nullptr, nullptr, nullptr,
      256, 0, 0);

  // g6: C2 = scatter(EA @ e2w2^T + e2b2) * gmax2
  gemm_fused<2><<<256, 512, 0, stream>>>(
      EA, WTe2b, e2b2, C2, rm2, gmax2, CAP, WSZ, HID,
      nullptr, nullptr, nullptr, nullptr, nullptr, nullptr, nullptr, nullptr, nullptr,
      256, 0, 0);

  // final: sent = mean_s(H) + mean_s(C2) @ w3 + b3  (mean commutes with w3)
  meanHC_kernel<<<dim3(2, 8, 16), 256, 0, stream>>>(H, C2, pH, pC);
  sent_kernel<<<32, 256, 0, stream>>>(pH, pC, WT + (size_t)2 * WSZ, b3, sent);
  loss_kernel<<<1, 1024, 0, stream>>>(sent, y, (float*)d_out);
}

// Round 11
// 225.971 us; speedup vs baseline: 1.4401x; 1.4401x over previous
//
#include <hip/hip_runtime.h>

#define TOK 4096
#define HID 1024
#define NEXP 8
#define CAP 512
#define WSZ 1048576  // HID*HID

typedef _Float16 f16;
typedef f16 f16x8 __attribute__((ext_vector_type(8)));
typedef f16 f16x4 __attribute__((ext_vector_type(4)));
typedef f16 f16x2 __attribute__((ext_vector_type(2)));
typedef float f32x4 __attribute__((ext_vector_type(4)));

typedef const __attribute__((address_space(1))) void gvoid;
typedef __attribute__((address_space(3))) void lvoid;

__device__ __forceinline__ void gld16(const void* g, void* l) {
  __builtin_amdgcn_global_load_lds((gvoid*)g, (lvoid*)l, 16, 0, 0);
}

// ---------------------------------------------------------------------------
// Fused GEMM + weight-transpose kernel, 256 threads, 48KB LDS -> 3 blocks/CU
// so transpose tail blocks CO-RESIDE with GEMM blocks (true overlap).
// Blocks [0, nGemm=512): MFMA f16 GEMM tile 64x128, BK=64, 4 waves, wave-tile
//   64x32 (4x2 frags). Bijective XCD swizzle: XCD x owns by in [8x,8x+8)
//   (= one expert for expert GEMMs). T4 counted-vmcnt 2-phase: stage(t+1)
//   [6 insts/wave] -> s_waitcnt vmcnt(6) -> barrier -> MFMA -> barrier.
// Blocks [nGemm, nGemm+nTrans): transpose-cast 64x64 tiles of nTrans/256
//   contiguous [1024][1024] f32 matrices -> [n][k] f16.
// MODE 0: C[r][col]=v; MODE 1: A gathered via rowmap (-1 -> zero row TOK);
// MODE 2: C[rowmap[r]][col] = v * gmax[rowmap[r]] (skip rowmap=-1)
// LDS rows 64 f16 XOR-swizzled chunk^=(row&7) via pre-swizzled global src.
// ---------------------------------------------------------------------------
template<int MODE>
__global__ __launch_bounds__(256, 3) void gemm_fused(
    const f16* __restrict__ A, const f16* __restrict__ Bt,
    const float* __restrict__ bias, f16* __restrict__ C,
    const int* __restrict__ rowmap, const float* __restrict__ gmax,
    int rowsPerExpert, long bStride, int biasStride,
    const float* __restrict__ tsrc, f16* __restrict__ tdst, int nGemm)
{
  __shared__ __align__(16) unsigned char smem[49152];
  const int tid = threadIdx.x;

  if ((int)blockIdx.x >= nGemm) {
    // ---------------- transpose-cast role (64x64 tile) ----------------
    float (*t)[65] = (float (*)[65])smem;    // 16.6 KB of the union
    const int tb = blockIdx.x - nGemm;
    const int mat = tb >> 8, t8 = tb & 255;
    const int kb = (t8 >> 4) * 64, nb = (t8 & 15) * 64;
    const float* src = tsrc + (size_t)mat * WSZ;
    f16* d = tdst + (size_t)mat * WSZ;
    const int rr = tid >> 4, c4 = (tid & 15) * 4;
    float4 v[4];
    #pragma unroll
    for (int p = 0; p < 4; ++p)
      v[p] = *(const float4*)&src[(size_t)(kb + p * 16 + rr) * HID + nb + c4];
    #pragma unroll
    for (int p = 0; p < 4; ++p) {
      t[p * 16 + rr][c4 + 0] = v[p].x;
      t[p * 16 + rr][c4 + 1] = v[p].y;
      t[p * 16 + rr][c4 + 2] = v[p].z;
      t[p * 16 + rr][c4 + 3] = v[p].w;
    }
    __syncthreads();
    #pragma unroll
    for (int half = 0; half < 2; ++half) {
      const int p = half * 256 + tid;
      const int n = p >> 3, kc = p & 7;
      f16x8 o;
      #pragma unroll
      for (int j = 0; j < 8; ++j) o[j] = (f16)t[kc * 8 + j][n];
      *(f16x8*)&d[(size_t)(nb + n) * HID + kb + kc * 8] = o;
    }
    return;
  }

  // ---------------- GEMM role (round-6 proven geometry) ----------------
  f16* As0 = (f16*)smem;              // [2][64*64]  f16 (16 KB)
  f16* Bs0 = (f16*)(smem + 16384);    // [2][128*64] f16 (32 KB)
  const int w = tid >> 6, l = tid & 63;

  // bijective XCD swizzle: XCD x owns by in [8x, 8x+8), all bx
  const int orig = blockIdx.x;                 // 0..511
  const int sw = (orig & 7) * 64 + (orig >> 3);
  const int bx = sw & 7, by = sw >> 3;
  const int e = (by * 64) / rowsPerExpert;

  const int lr = l >> 3;                    // row within 8-row staging inst
  const int chunkSw = ((l & 7) ^ lr) * 8;   // pre-swizzled k-chunk

  // A staging: wave w owns rows w*16 .. w*16+15 (2 insts)
  const f16* pa[2];
  #pragma unroll
  for (int i = 0; i < 2; ++i) {
    int r = by * 64 + w * 16 + i * 8 + lr;
    long tok = r;
    if (MODE == 1) { int t = rowmap[r]; tok = (t < 0) ? (long)TOK : (long)t; }
    pa[i] = A + tok * HID + chunkSw;
  }
  // B staging: wave w owns n-rows w*32 .. w*32+31 (4 insts)
  const f16* pb = Bt + (size_t)e * bStride
                + (size_t)(bx * 128 + w * 32 + lr) * HID + chunkSw;

  f32x4 acc[4][2];
  #pragma unroll
  for (int i = 0; i < 4; ++i)
    #pragma unroll
    for (int j = 0; j < 2; ++j) acc[i][j] = (f32x4){0.f, 0.f, 0.f, 0.f};

  const int g = l >> 4, c = l & 15, sa = c & 7;

  // prologue: stage k=0 into buf 0 (6 insts/wave)
  {
    f16* ab = As0 + (w * 16) * 64;
    f16* bb = Bs0 + (w * 32) * 64;
    #pragma unroll
    for (int i = 0; i < 2; ++i) gld16(pa[i], ab + i * 8 * 64);
    #pragma unroll
    for (int i = 0; i < 4; ++i) gld16(pb + (size_t)(i * 8) * HID, bb + i * 8 * 64);
  }

  int cur = 0;
  for (int t = 0; t < 15; ++t) {
    {  // stage tile t+1 into buf cur^1 (6 loads/wave stay in flight)
      const int k0 = (t + 1) * 64;
      f16* ab = As0 + (cur ^ 1) * 4096 + (w * 16) * 64;
      f16* bb = Bs0 + (cur ^ 1) * 8192 + (w * 32) * 64;
      #pragma unroll
      for (int i = 0; i < 2; ++i) gld16(pa[i] + k0, ab + i * 8 * 64);
      #pragma unroll
      for (int i = 0; i < 4; ++i) gld16(pb + (size_t)(i * 8) * HID + k0, bb + i * 8 * 64);
    }
    asm volatile("s_waitcnt vmcnt(6)" ::: "memory");  // tile t landed
    asm volatile("s_barrier" ::: "memory");           // buf[cur] full for all
    __builtin_amdgcn_s_setprio(1);
    #pragma unroll
    for (int h = 0; h < 2; ++h) {
      const int q = ((h * 4 + g) ^ sa) * 8;
      f16x8 af[4], bf[2];
      #pragma unroll
      for (int mi = 0; mi < 4; ++mi)
        af[mi] = *(const f16x8*)&As0[cur * 4096 + (mi * 16 + c) * 64 + q];
      #pragma unroll
      for (int ni = 0; ni < 2; ++ni)
        bf[ni] = *(const f16x8*)&Bs0[cur * 8192 + (w * 32 + ni * 16 + c) * 64 + q];
      #pragma unroll
      for (int mi = 0; mi < 4; ++mi)
        #pragma unroll
        for (int ni = 0; ni < 2; ++ni)
          acc[mi][ni] = __builtin_amdgcn_mfma_f32_16x16x32_f16(
              af[mi], bf[ni], acc[mi][ni], 0, 0, 0);
    }
    __builtin_amdgcn_s_setprio(0);
    asm volatile("s_barrier" ::: "memory");  // buf[cur] free for overwrite
    cur ^= 1;
  }
  // final tile
  asm volatile("s_waitcnt vmcnt(0)" ::: "memory");
  asm volatile("s_barrier" ::: "memory");
  __builtin_amdgcn_s_setprio(1);
  #pragma unroll
  for (int h = 0; h < 2; ++h) {
    const int q = ((h * 4 + g) ^ sa) * 8;
    f16x8 af[4], bf[2];
    #pragma unroll
    for (int mi = 0; mi < 4; ++mi)
      af[mi] = *(const f16x8*)&As0[cur * 4096 + (mi * 16 + c) * 64 + q];
    #pragma unroll
    for (int ni = 0; ni < 2; ++ni)
      bf[ni] = *(const f16x8*)&Bs0[cur * 8192 + (w * 32 + ni * 16 + c) * 64 + q];
    #pragma unroll
    for (int mi = 0; mi < 4; ++mi)
      #pragma unroll
      for (int ni = 0; ni < 2; ++ni)
        acc[mi][ni] = __builtin_amdgcn_mfma_f32_16x16x32_f16(
            af[mi], bf[ni], acc[mi][ni], 0, 0, 0);
  }
  __builtin_amdgcn_s_setprio(0);

  // epilogue: D col = lane&15, row = (lane>>4)*4 + reg
  int tk[4][4];
  float gv[4][4];
  if (MODE == 2) {
    #pragma unroll
    for (int mi = 0; mi < 4; ++mi)
      #pragma unroll
      for (int rr = 0; rr < 4; ++rr) {
        int r = by * 64 + mi * 16 + g * 4 + rr;
        int t = rowmap[r];
        tk[mi][rr] = t;
        gv[mi][rr] = (t >= 0) ? gmax[t] : 0.f;
      }
  }
  #pragma unroll
  for (int ni = 0; ni < 2; ++ni) {
    const int col = bx * 128 + w * 32 + ni * 16 + c;
    const float bv = bias[(size_t)e * biasStride + col];
    #pragma unroll
    for (int mi = 0; mi < 4; ++mi) {
      #pragma unroll
      for (int rr = 0; rr < 4; ++rr) {
        const float v = acc[mi][ni][rr] + bv;
        if (MODE == 2) {
          if (tk[mi][rr] >= 0)
            C[(size_t)tk[mi][rr] * HID + col] = (f16)(v * gv[mi][rr]);
        } else {
          const int row = by * 64 + mi * 16 + g * 4 + rr;
          C[(size_t)row * HID + col] = (f16)v;
        }
      }
    }
  }
}

// ---------------------------------------------------------------------------
// prep2: blocks [0,2048): cast x f32->f16, zero C1/C2 + pad rows.
//        blocks [2048,2816): transpose-cast w1,w2,w3 (64x64 tiles).
// ---------------------------------------------------------------------------
__global__ __launch_bounds__(256) void prep2(
    const float* __restrict__ x, f16* __restrict__ X0,
    f16* __restrict__ c1, f16* __restrict__ c2,
    f16* __restrict__ p1, f16* __restrict__ p2,
    const float* __restrict__ w1, const float* __restrict__ w2,
    const float* __restrict__ w3, f16* __restrict__ WT)
{
  __shared__ float t[64][65];
  const int tid = threadIdx.x;
  if ((int)blockIdx.x < 2048) {
    const f16x8 zz = {0, 0, 0, 0, 0, 0, 0, 0};
    #pragma unroll
    for (int it = 0; it < 2; ++it) {
      const size_t i = (size_t)blockIdx.x * 256 + tid + (size_t)it * 524288;
      float4 v = *(const float4*)&x[i * 4];
      f16x4 o = {(f16)v.x, (f16)v.y, (f16)v.z, (f16)v.w};
      *(f16x4*)&X0[i * 4] = o;
      if (i < 524288) { ((f16x8*)c1)[i] = zz; ((f16x8*)c2)[i] = zz; }
      if (i < 128)    { ((f16x8*)p1)[i] = zz; ((f16x8*)p2)[i] = zz; }
    }
    return;
  }
  const int zb = blockIdx.x - 2048;
  const int z = zb >> 8, t8 = zb & 255;
  const float* src = (z == 0) ? w1 : (z == 1) ? w2 : w3;
  f16* d = WT + (size_t)z * WSZ;
  const int kb = (t8 >> 4) * 64, nb = (t8 & 15) * 64;
  const int rr = tid >> 4, c4 = (tid & 15) * 4;
  float4 v[4];
  #pragma unroll
  for (int p = 0; p < 4; ++p)
    v[p] = *(const float4*)&src[(size_t)(kb + p * 16 + rr) * HID + nb + c4];
  #pragma unroll
  for (int p = 0; p < 4; ++p) {
    t[p * 16 + rr][c4 + 0] = v[p].x;
    t[p * 16 + rr][c4 + 1] = v[p].y;
    t[p * 16 + rr][c4 + 2] = v[p].z;
    t[p * 16 + rr][c4 + 3] = v[p].w;
  }
  __syncthreads();
  #pragma unroll
  for (int half = 0; half < 2; ++half) {
    const int p = half * 256 + tid;
    const int n = p >> 3, kc = p & 7;
    f16x8 o;
    #pragma unroll
    for (int j = 0; j < 8; ++j) o[j] = (f16)t[kc * 8 + j][n];
    *(f16x8*)&d[(size_t)(nb + n) * HID + kb + kc * 8] = o;
  }
}

// ---------------------------------------------------------------------------
// Gating: 8 tokens/block, 32 lanes/token, f32 accum, float4 wg loads.
// ---------------------------------------------------------------------------
__global__ __launch_bounds__(256) void gate_kernel(
    const f16* __restrict__ act, const float* __restrict__ wg,
    int* __restrict__ idx, float* __restrict__ gmax)
{
  const int tid = threadIdx.x;
  const int tok = blockIdx.x * 8 + (tid >> 5);
  const int sl = tid & 31;
  const f16* row = act + (size_t)tok * HID + sl * 32;
  float xv[32];
  #pragma unroll
  for (int v = 0; v < 4; ++v) {
    f16x8 hv = *(const f16x8*)(row + v * 8);
    #pragma unroll
    for (int j = 0; j < 8; ++j) xv[v * 8 + j] = (float)hv[j];
  }
  float p[NEXP];
  #pragma unroll
  for (int e = 0; e < NEXP; ++e) p[e] = 0.f;
  const float4* w4 = (const float4*)(wg + (size_t)(sl * 32) * NEXP);
  #pragma unroll
  for (int j = 0; j < 32; ++j) {
    float4 lo = w4[2 * j], hi = w4[2 * j + 1];
    p[0] += xv[j] * lo.x; p[1] += xv[j] * lo.y;
    p[2] += xv[j] * lo.z; p[3] += xv[j] * lo.w;
    p[4] += xv[j] * hi.x; p[5] += xv[j] * hi.y;
    p[6] += xv[j] * hi.z; p[7] += xv[j] * hi.w;
  }
  #pragma unroll
  for (int m = 1; m < 32; m <<= 1) {
    #pragma unroll
    for (int e = 0; e < NEXP; ++e) p[e] += __shfl_xor(p[e], m, 64);
  }
  if (sl == 0) {
    float mx = p[0]; int am = 0;
    #pragma unroll
    for (int e = 1; e < NEXP; ++e)
      if (p[e] > mx) { mx = p[e]; am = e; }
    float s = 0.f;
    #pragma unroll
    for (int e = 0; e < NEXP; ++e) s += expf(p[e] - mx);
    idx[tok] = am;
    gmax[tok] = 1.f / s;
  }
}

// ---------------------------------------------------------------------------
__global__ __launch_bounds__(512) void scan_kernel(
    const int* __restrict__ idx, int* __restrict__ rowmap)
{
  __shared__ int sidx[TOK];
  const int tid = threadIdx.x;
  for (int i = tid; i < TOK; i += 512) sidx[i] = idx[i];
  for (int i = tid; i < NEXP * CAP; i += 512) rowmap[i] = -1;
  __syncthreads();
  const int wave = tid >> 6, lane = tid & 63;
  int running = 0;
  for (int ch = 0; ch < TOK / 64; ++ch) {
    int t = ch * 64 + lane;
    bool flag = (sidx[t] == wave);
    unsigned long long m = __ballot(flag);
    int pos = running + __popcll(m & ((1ull << lane) - 1ull));
    if (flag && pos < CAP) rowmap[wave * CAP + pos] = t;
    running += __popcll(m);
  }
}

// ---------------------------------------------------------------------------
// meanHC: partial sums over 32-s chunks of H and C2.  grid (2,8,16).
// ---------------------------------------------------------------------------
__global__ __launch_bounds__(256) void meanHC_kernel(
    const f16* __restrict__ Hb, const f16* __restrict__ C2b,
    float* __restrict__ pH, float* __restrict__ pC)
{
  const int h2 = blockIdx.x * 256 + threadIdx.x;  // 0..511
  const int b = blockIdx.y, sc = blockIdx.z;
  const f16x2* pa = (const f16x2*)(Hb + ((size_t)b * 512 + sc * 32) * HID) + h2;
  const f16x2* pc = (const f16x2*)(C2b + ((size_t)b * 512 + sc * 32) * HID) + h2;
  float a0 = 0.f, a1 = 0.f, c0 = 0.f, c1 = 0.f;
  #pragma unroll 4
  for (int s = 0; s < 32; ++s) {
    f16x2 va = pa[(size_t)s * 512];
    f16x2 vc = pc[(size_t)s * 512];
    a0 += (float)va[0]; a1 += (float)va[1];
    c0 += (float)vc[0]; c1 += (float)vc[1];
  }
  float* oh = pH + ((size_t)sc * 8 + b) * HID;
  float* oc = pC + ((size_t)sc * 8 + b) * HID;
  oh[h2 * 2] = a0; oh[h2 * 2 + 1] = a1;
  oc[h2 * 2] = c0; oc[h2 * 2 + 1] = c1;
}

// ---------------------------------------------------------------------------
// sent[b][col] = mean_s H + b3[col] + (mean_s C2) @ w3   (exact commute).
// ---------------------------------------------------------------------------
__global__ __launch_bounds__(256) void sent_kernel(
    const float* __restrict__ pH, const float* __restrict__ pC,
    const f16* __restrict__ WT2, const float* __restrict__ b3,
    float* __restrict__ sent)
{
  __shared__ float c2m[HID];
  const int tid = threadIdx.x;
  const int b = blockIdx.x >> 2, ch = blockIdx.x & 3;
  for (int kk = tid; kk < HID; kk += 256) {
    float s = 0.f;
    #pragma unroll
    for (int sc = 0; sc < 16; ++sc) s += pC[((size_t)sc * 8 + b) * HID + kk];
    c2m[kk] = s * (1.f / 512.f);
  }
  __syncthreads();
  const int col = ch * 256 + tid;
  float hv = 0.f;
  #pragma unroll
  for (int sc = 0; sc < 16; ++sc) hv += pH[((size_t)sc * 8 + b) * HID + col];
  float acc = hv * (1.f / 512.f) + b3[col];
  const f16* wrow = WT2 + (size_t)col * HID;
  for (int k0 = 0; k0 < HID; k0 += 8) {
    f16x8 wv = *(const f16x8*)(wrow + k0);
    #pragma unroll
    for (int j = 0; j < 8; ++j) acc += c2m[k0 + j] * (float)wv[j];
  }
  sent[b * HID + col] = acc;
}

// ---------------------------------------------------------------------------
__global__ __launch_bounds__(1024) void loss_kernel(
    const float* __restrict__ sent, const int* __restrict__ y,
    float* __restrict__ out)
{
  __shared__ float red[17];
  const int tid = threadIdx.x;
  const int wid = tid >> 6, lane = tid & 63;
  float loss = 0.0f;
  for (int b = 0; b < 8; ++b) {
    const float v = sent[b * HID + tid];
    float m = v;
    #pragma unroll
    for (int o = 32; o; o >>= 1) m = fmaxf(m, __shfl_xor(m, o, 64));
    if (lane == 0) red[wid] = m;
    __syncthreads();
    if (tid < 16) {
      float mm = red[tid];
      #pragma unroll
      for (int o = 8; o; o >>= 1) mm = fmaxf(mm, __shfl_xor(mm, o, 16));
      if (tid == 0) red[16] = mm;
    }
    __syncthreads();
    const float M = red[16];
    float s = expf(v - M);
    #pragma unroll
    for (int o = 32; o; o >>= 1) s += __shfl_xor(s, o, 64);
    __syncthreads();
    if (lane == 0) red[wid] = s;
    __syncthreads();
    if (tid < 16) {
      float ss = red[tid];
      #pragma unroll
      for (int o = 8; o; o >>= 1) ss += __shfl_xor(ss, o, 16);
      if (tid == 0) red[16] = M + logf(ss);
    }
    __syncthreads();
    if (tid == 0) loss += -(sent[b * HID + y[b]] - red[16]);
    __syncthreads();
  }
  if (tid == 0) out[0] = loss * (1.0f / 8.0f);
}

// ---------------------------------------------------------------------------
extern "C" void kernel_launch(void* const* d_in, const int* in_sizes, int n_in,
                              void* d_out, int out_size, void* d_ws, size_t ws_size,
                              hipStream_t stream)
{
  const float* x    = (const float*)d_in[0];
  const int*   y    = (const int*)d_in[1];
  const float* w1   = (const float*)d_in[2];
  const float* b1   = (const float*)d_in[3];
  const float* w2   = (const float*)d_in[4];
  const float* b2   = (const float*)d_in[5];
  const float* w3   = (const float*)d_in[6];
  const float* b3   = (const float*)d_in[7];
  const float* wg1  = (const float*)d_in[8];
  const float* e1w1 = (const float*)d_in[9];
  const float* e1b1 = (const float*)d_in[10];
  const float* e1w2 = (const float*)d_in[11];
  const float* e1b2 = (const float*)d_in[12];
  const float* wg2  = (const float*)d_in[13];
  const float* e2w1 = (const float*)d_in[14];
  const float* e2b1 = (const float*)d_in[15];
  const float* e2w2 = (const float*)d_in[16];
  const float* e2b2 = (const float*)d_in[17];

  // workspace (~137 MB)
  f16* WT = (f16*)d_ws;                          // 35 x [1024][1024] f16
  f16* X0 = WT + (size_t)35 * WSZ;               // [4096][1024]
  f16* H  = X0 + (size_t)TOK * HID;              // [4097][1024] (pad row)
  f16* EA = H + (size_t)(TOK + 1) * HID;         // [4096][1024]
  f16* C1 = EA + (size_t)TOK * HID;              // [4096][1024]
  f16* M1 = C1 + (size_t)TOK * HID;              // [4097][1024] (pad row)
  f16* C2 = M1 + (size_t)(TOK + 1) * HID;        // [4096][1024]
  float* gmax  = (float*)(C2 + (size_t)TOK * HID);
  int* idx     = (int*)(gmax + TOK);
  int* rowmap  = idx + TOK;
  float* sent  = (float*)(rowmap + NEXP * CAP);
  float* pH    = sent + 8 * HID;                 // [16][8][1024]
  float* pC    = pH + 16 * 8 * HID;              // [16][8][1024]

  f16* WTe1a = WT + (size_t)3 * WSZ;
  f16* WTe1b = WT + (size_t)11 * WSZ;
  f16* WTe2a = WT + (size_t)19 * WSZ;
  f16* WTe2b = WT + (size_t)27 * WSZ;

  const int FUSED = 512 + 8 * 256;   // 512 gemm + 2048 transpose tail blocks

  // prep: x cast + zeros + w1/w2/w3 transposes
  prep2<<<2816, 256, 0, stream>>>(x, X0, C1, C2,
                                  H + (size_t)TOK * HID, M1 + (size_t)TOK * HID,
                                  w1, w2, w3, WT);

  // g1: H = X0 @ w1^T + b1  (+ transpose e1w1, overlapped)
  gemm_fused<0><<<FUSED, 256, 0, stream>>>(X0, WT, b1, H, nullptr, nullptr,
                                           TOK, 0, 0, e1w1, WTe1a, 512);

  // ---- MoE layer 1 ----
  gate_kernel<<<512, 256, 0, stream>>>(H, wg1, idx, gmax);
  scan_kernel<<<1, 512, 0, stream>>>(idx, rowmap);
  gemm_fused<1><<<FUSED, 256, 0, stream>>>(H, WTe1a, e1b1, EA, rowmap, nullptr,
                                           CAP, WSZ, HID, e1w2, WTe1b, 512);
  gemm_fused<2><<<FUSED, 256, 0, stream>>>(EA, WTe1b, e1b2, C1, rowmap, gmax,
                                           CAP, WSZ, HID, e2w1, WTe2a, 512);

  // g4: M1 = C1 @ w2^T + b2  (+ transpose e2w2, overlapped)
  gemm_fused<0><<<FUSED, 256, 0, stream>>>(C1, WT + (size_t)1 * WSZ, b2, M1,
                                           nullptr, nullptr, TOK, 0, 0,
                                           e2w2, WTe2b, 512);

  // ---- MoE layer 2 ----
  gate_kernel<<<512, 256, 0, stream>>>(M1, wg2, idx, gmax);
  scan_kernel<<<1, 512, 0, stream>>>(idx, rowmap);
  gemm_fused<1><<<512, 256, 0, stream>>>(M1, WTe2a, e2b1, EA, rowmap, nullptr,
                                         CAP, WSZ, HID, w1, WT, 512);
  gemm_fused<2><<<512, 256, 0, stream>>>(EA, WTe2b, e2b2, C2, rowmap, gmax,
                                         CAP, WSZ, HID, w1, WT, 512);

  // final: sent = mean_s(H) + mean_s(C2) @ w3 + b3  (mean commutes with w3)
  meanHC_kernel<<<dim3(2, 8, 16), 256, 0, stream>>>(H, C2, pH, pC);
  sent_kernel<<<32, 256, 0, stream>>>(pH, pC, WT + (size_t)2 * WSZ, b3, sent);
  loss_kernel<<<1, 1024, 0, stream>>>(sent, y, (float*)d_out);
}

// Round 12
// 215.400 us; speedup vs baseline: 1.5108x; 1.0491x over previous
//
#include <hip/hip_runtime.h>

#define TOK 4096
#define HID 1024
#define NEXP 8
#define CAP 512
#define WSZ 1048576  // HID*HID

typedef _Float16 f16;
typedef f16 f16x8 __attribute__((ext_vector_type(8)));
typedef f16 f16x4 __attribute__((ext_vector_type(4)));
typedef f16 f16x2 __attribute__((ext_vector_type(2)));
typedef float f32x4 __attribute__((ext_vector_type(4)));

typedef const __attribute__((address_space(1))) void gvoid;
typedef __attribute__((address_space(3))) void lvoid;

__device__ __forceinline__ void gld16(const void* g, void* l) {
  __builtin_amdgcn_global_load_lds((gvoid*)g, (lvoid*)l, 16, 0, 0);
}

// ---------------------------------------------------------------------------
// Pipelined transpose-cast of one 64n x 256k slab of a [1024k][1024n] f32
// matrix into [n][k] f16. 512 threads. Uses global_load_lds staging into a
// double-buffered [64][64] f32 LDS tile with counted vmcnt (T4) and an XOR
// chunk-swizzle c^=(r>>2)&15 applied on the SOURCE address (global_load_lds
// writes linearly; read side applies the same involution). Readout banks are
// exactly 2-way (free). Stores: 8 consecutive lanes write 128B contiguous.
// vmcnt schedule (per-thread issue FIFO: 2 loads/stage, 1 store/readout):
//   iter0: [S0,S0,S1,S1]          -> certify S0 => vmcnt(2)
//   iter1: [S1,S1,st0,S2,S2]      -> certify S1 => vmcnt(3)
//   iter2: [S2,S2,st1,S3,S3](+st0)-> certify S2 => vmcnt(3)
//   iter3: [S3,S3,st2]            -> certify S3 => vmcnt(1)
// ---------------------------------------------------------------------------
__device__ __forceinline__ void wtrans(const float* __restrict__ src,
                                       f16* __restrict__ dst,
                                       int nb, int kb0, float* lds, int tid)
{
  const int n = tid >> 3, seg = tid & 7;
  // stage subtile ks into lds buffer buf
  #define WSTAGE(ks, buf)                                                    \
    {                                                                        \
      _Pragma("unroll")                                                      \
      for (int i = 0; i < 2; ++i) {                                          \
        int p = i * 512 + tid;                                               \
        int r = p >> 4, c = p & 15;                                          \
        int cg = c ^ ((r >> 2) & 15);                                        \
        gld16(src + (size_t)(kb0 + (ks) * 64 + r) * HID + nb + cg * 4,       \
              lds + (buf) * 4096 + p * 4);                                   \
      }                                                                      \
    }
  WSTAGE(0, 0);
  #pragma unroll
  for (int s = 0; s < 4; ++s) {
    if (s == 0)      { WSTAGE(1, 1); asm volatile("s_waitcnt vmcnt(2)" ::: "memory"); }
    else if (s == 1) { WSTAGE(2, 0); asm volatile("s_waitcnt vmcnt(3)" ::: "memory"); }
    else if (s == 2) { WSTAGE(3, 1); asm volatile("s_waitcnt vmcnt(3)" ::: "memory"); }
    else             {               asm volatile("s_waitcnt vmcnt(1)" ::: "memory"); }
    asm volatile("s_barrier" ::: "memory");
    const float* B = lds + (s & 1) * 4096;
    f16x8 o;
    #pragma unroll
    for (int j = 0; j < 8; ++j) {
      int r = seg * 8 + j;
      int cl = (n >> 2) ^ ((r >> 2) & 15);
      o[j] = (f16)B[r * 64 + cl * 4 + (n & 3)];
    }
    *(f16x8*)&dst[(size_t)(nb + n) * HID + kb0 + s * 64 + seg * 8] = o;
    asm volatile("s_barrier" ::: "memory");
  }
  #undef WSTAGE
}

// ---------------------------------------------------------------------------
// Fused GEMM + weight-transpose kernel (round-9 proven GEMM).
// Blocks [0, nGemm=256): MFMA f16 GEMM tile 128x128, BK=64, 512 thr = 8
//   waves, wave-tile 64x32. Bijective XCD swizzle (by quads -> one expert
//   per XCD for expert GEMMs). Counted-vmcnt 2-phase pipeline.
// Blocks [nGemm, nGemm+512): pipelined transpose-cast (wtrans) of 8
//   contiguous [1024][1024] f32 matrices; 64 slab-blocks per matrix.
// MODE 0: C[r][col]=v; MODE 1: A gathered via rowmap (-1 -> zero row TOK);
// MODE 2: C[rowmap[r]][col] = v * gmax[rowmap[r]] (skip rowmap=-1)
// ---------------------------------------------------------------------------
template<int MODE>
__global__ __launch_bounds__(512, 1) void gemm_fused(
    const f16* __restrict__ A, const f16* __restrict__ Bt,
    const float* __restrict__ bias, f16* __restrict__ C,
    const int* __restrict__ rowmap, const float* __restrict__ gmax,
    int rowsPerExpert, long bStride, int biasStride,
    const float* __restrict__ tsrc, f16* __restrict__ tdst, int nGemm)
{
  __shared__ __align__(16) unsigned char smem[65536];
  const int tid = threadIdx.x;

  if ((int)blockIdx.x >= nGemm) {
    const int tb = blockIdx.x - nGemm;
    const int mat = tb >> 6, slab = tb & 63;
    wtrans(tsrc + (size_t)mat * WSZ, tdst + (size_t)mat * WSZ,
           (slab & 15) * 64, (slab >> 4) * 256, (float*)smem, tid);
    return;
  }

  // ---------------- GEMM role ----------------
  f16* As0 = (f16*)smem;             // [2][128*64] f16
  f16* Bs0 = (f16*)(smem + 32768);   // [2][128*64] f16
  const int w = tid >> 6, l = tid & 63;
  const int wr = w >> 2, wc = w & 3;

  const int orig = blockIdx.x;                 // 0..255
  const int sw = (orig & 7) * 32 + (orig >> 3);
  const int bx = sw & 7, by = sw >> 3;
  const int e = (by * 128) / rowsPerExpert;

  const int lr = l >> 3;
  const int chunkSw = ((l & 7) ^ lr) * 8;

  const f16* pst[4];
  if (w < 4) {
    #pragma unroll
    for (int i = 0; i < 4; ++i) {
      int r = by * 128 + w * 32 + i * 8 + lr;
      long tok = r;
      if (MODE == 1) { int t = rowmap[r]; tok = (t < 0) ? (long)TOK : (long)t; }
      pst[i] = A + tok * HID + chunkSw;
    }
  } else {
    #pragma unroll
    for (int i = 0; i < 4; ++i)
      pst[i] = Bt + (size_t)e * bStride
             + (size_t)(bx * 128 + (w - 4) * 32 + i * 8 + lr) * HID + chunkSw;
  }

  f32x4 acc[4][2];
  #pragma unroll
  for (int i = 0; i < 4; ++i)
    #pragma unroll
    for (int j = 0; j < 2; ++j) acc[i][j] = (f32x4){0.f, 0.f, 0.f, 0.f};

  const int g = l >> 4, c = l & 15, sa = c & 7;

  {
    f16* db = (w < 4) ? As0 + (w * 32) * 64 : Bs0 + ((w - 4) * 32) * 64;
    #pragma unroll
    for (int i = 0; i < 4; ++i) gld16(pst[i], db + i * 8 * 64);
  }

  int cur = 0;
  for (int t = 0; t < 15; ++t) {
    {
      const int k0 = (t + 1) * 64;
      f16* db = (w < 4) ? As0 + ((cur ^ 1) * 8192) + (w * 32) * 64
                        : Bs0 + ((cur ^ 1) * 8192) + ((w - 4) * 32) * 64;
      #pragma unroll
      for (int i = 0; i < 4; ++i) gld16(pst[i] + k0, db + i * 8 * 64);
    }
    asm volatile("s_waitcnt vmcnt(4)" ::: "memory");
    asm volatile("s_barrier" ::: "memory");
    __builtin_amdgcn_s_setprio(1);
    #pragma unroll
    for (int h = 0; h < 2; ++h) {
      const int q = ((h * 4 + g) ^ sa) * 8;
      f16x8 af[4], bf[2];
      #pragma unroll
      for (int mi = 0; mi < 4; ++mi)
        af[mi] = *(const f16x8*)&As0[cur * 8192 + (wr * 64 + mi * 16 + c) * 64 + q];
      #pragma unroll
      for (int ni = 0; ni < 2; ++ni)
        bf[ni] = *(const f16x8*)&Bs0[cur * 8192 + (wc * 32 + ni * 16 + c) * 64 + q];
      #pragma unroll
      for (int mi = 0; mi < 4; ++mi)
        #pragma unroll
        for (int ni = 0; ni < 2; ++ni)
          acc[mi][ni] = __builtin_amdgcn_mfma_f32_16x16x32_f16(
              af[mi], bf[ni], acc[mi][ni], 0, 0, 0);
    }
    __builtin_amdgcn_s_setprio(0);
    asm volatile("s_barrier" ::: "memory");
    cur ^= 1;
  }
  asm volatile("s_waitcnt vmcnt(0)" ::: "memory");
  asm volatile("s_barrier" ::: "memory");
  __builtin_amdgcn_s_setprio(1);
  #pragma unroll
  for (int h = 0; h < 2; ++h) {
    const int q = ((h * 4 + g) ^ sa) * 8;
    f16x8 af[4], bf[2];
    #pragma unroll
    for (int mi = 0; mi < 4; ++mi)
      af[mi] = *(const f16x8*)&As0[cur * 8192 + (wr * 64 + mi * 16 + c) * 64 + q];
    #pragma unroll
    for (int ni = 0; ni < 2; ++ni)
      bf[ni] = *(const f16x8*)&Bs0[cur * 8192 + (wc * 32 + ni * 16 + c) * 64 + q];
    #pragma unroll
    for (int mi = 0; mi < 4; ++mi)
      #pragma unroll
      for (int ni = 0; ni < 2; ++ni)
        acc[mi][ni] = __builtin_amdgcn_mfma_f32_16x16x32_f16(
            af[mi], bf[ni], acc[mi][ni], 0, 0, 0);
  }
  __builtin_amdgcn_s_setprio(0);

  int tk[4][4];
  float gv[4][4];
  if (MODE == 2) {
    #pragma unroll
    for (int mi = 0; mi < 4; ++mi)
      #pragma unroll
      for (int rr = 0; rr < 4; ++rr) {
        int r = by * 128 + wr * 64 + mi * 16 + g * 4 + rr;
        int t = rowmap[r];
        tk[mi][rr] = t;
        gv[mi][rr] = (t >= 0) ? gmax[t] : 0.f;
      }
  }
  #pragma unroll
  for (int ni = 0; ni < 2; ++ni) {
    const int col = bx * 128 + wc * 32 + ni * 16 + c;
    const float bv = bias[(size_t)e * biasStride + col];
    #pragma unroll
    for (int mi = 0; mi < 4; ++mi) {
      #pragma unroll
      for (int rr = 0; rr < 4; ++rr) {
        const float v = acc[mi][ni][rr] + bv;
        if (MODE == 2) {
          if (tk[mi][rr] >= 0)
            C[(size_t)tk[mi][rr] * HID + col] = (f16)(v * gv[mi][rr]);
        } else {
          const int row = by * 128 + wr * 64 + mi * 16 + g * 4 + rr;
          C[(size_t)row * HID + col] = (f16)v;
        }
      }
    }
  }
}

// ---------------------------------------------------------------------------
// prep2 (512 thr): blocks [0,1024): cast x f32->f16, zero C1/C2 + pad rows.
//                  blocks [1024,1216): pipelined transpose of w1,w2,w3.
// ---------------------------------------------------------------------------
__global__ __launch_bounds__(512) void prep2(
    const float* __restrict__ x, f16* __restrict__ X0,
    f16* __restrict__ c1, f16* __restrict__ c2,
    f16* __restrict__ p1, f16* __restrict__ p2,
    const float* __restrict__ w1, const float* __restrict__ w2,
    const float* __restrict__ w3, f16* __restrict__ WT)
{
  __shared__ __align__(16) float lds[2 * 4096];   // 32 KB
  const int tid = threadIdx.x;
  if ((int)blockIdx.x < 1024) {
    const f16x8 zz = {0, 0, 0, 0, 0, 0, 0, 0};
    const size_t i = (size_t)blockIdx.x * 512 + tid;   // 0..524287
    #pragma unroll
    for (int it = 0; it < 2; ++it) {
      const size_t idx = i + (size_t)it * 524288;
      float4 v = *(const float4*)&x[idx * 4];
      f16x4 o = {(f16)v.x, (f16)v.y, (f16)v.z, (f16)v.w};
      *(f16x4*)&X0[idx * 4] = o;
    }
    ((f16x8*)c1)[i] = zz;
    ((f16x8*)c2)[i] = zz;
    if (i < 128) { ((f16x8*)p1)[i] = zz; ((f16x8*)p2)[i] = zz; }
    return;
  }
  const int tb = blockIdx.x - 1024;
  const int z = tb >> 6, slab = tb & 63;
  const float* src = (z == 0) ? w1 : (z == 1) ? w2 : w3;
  wtrans(src, WT + (size_t)z * WSZ, (slab & 15) * 64, (slab >> 4) * 256,
         lds, tid);
}

// ---------------------------------------------------------------------------
// Gating: 8 tokens/block, 32 lanes/token, f32 accum, float4 wg loads.
// ---------------------------------------------------------------------------
__global__ __launch_bounds__(256) void gate_kernel(
    const f16* __restrict__ act, const float* __restrict__ wg,
    int* __restrict__ idx, float* __restrict__ gmax)
{
  const int tid = threadIdx.x;
  const int tok = blockIdx.x * 8 + (tid >> 5);
  const int sl = tid & 31;
  const f16* row = act + (size_t)tok * HID + sl * 32;
  float xv[32];
  #pragma unroll
  for (int v = 0; v < 4; ++v) {
    f16x8 hv = *(const f16x8*)(row + v * 8);
    #pragma unroll
    for (int j = 0; j < 8; ++j) xv[v * 8 + j] = (float)hv[j];
  }
  float p[NEXP];
  #pragma unroll
  for (int e = 0; e < NEXP; ++e) p[e] = 0.f;
  const float4* w4 = (const float4*)(wg + (size_t)(sl * 32) * NEXP);
  #pragma unroll
  for (int j = 0; j < 32; ++j) {
    float4 lo = w4[2 * j], hi = w4[2 * j + 1];
    p[0] += xv[j] * lo.x; p[1] += xv[j] * lo.y;
    p[2] += xv[j] * lo.z; p[3] += xv[j] * lo.w;
    p[4] += xv[j] * hi.x; p[5] += xv[j] * hi.y;
    p[6] += xv[j] * hi.z; p[7] += xv[j] * hi.w;
  }
  #pragma unroll
  for (int m = 1; m < 32; m <<= 1) {
    #pragma unroll
    for (int e = 0; e < NEXP; ++e) p[e] += __shfl_xor(p[e], m, 64);
  }
  if (sl == 0) {
    float mx = p[0]; int am = 0;
    #pragma unroll
    for (int e = 1; e < NEXP; ++e)
      if (p[e] > mx) { mx = p[e]; am = e; }
    float s = 0.f;
    #pragma unroll
    for (int e = 0; e < NEXP; ++e) s += expf(p[e] - mx);
    idx[tok] = am;
    gmax[tok] = 1.f / s;
  }
}

// ---------------------------------------------------------------------------
__global__ __launch_bounds__(512) void scan_kernel(
    const int* __restrict__ idx, int* __restrict__ rowmap)
{
  __shared__ int sidx[TOK];
  const int tid = threadIdx.x;
  for (int i = tid; i < TOK; i += 512) sidx[i] = idx[i];
  for (int i = tid; i < NEXP * CAP; i += 512) rowmap[i] = -1;
  __syncthreads();
  const int wave = tid >> 6, lane = tid & 63;
  int running = 0;
  for (int ch = 0; ch < TOK / 64; ++ch) {
    int t = ch * 64 + lane;
    bool flag = (sidx[t] == wave);
    unsigned long long m = __ballot(flag);
    int pos = running + __popcll(m & ((1ull << lane) - 1ull));
    if (flag && pos < CAP) rowmap[wave * CAP + pos] = t;
    running += __popcll(m);
  }
}

// ---------------------------------------------------------------------------
// meanHC: partial sums over 32-s chunks of H and C2.  grid (2,8,16).
// ---------------------------------------------------------------------------
__global__ __launch_bounds__(256) void meanHC_kernel(
    const f16* __restrict__ Hb, const f16* __restrict__ C2b,
    float* __restrict__ pH, float* __restrict__ pC)
{
  const int h2 = blockIdx.x * 256 + threadIdx.x;  // 0..511
  const int b = blockIdx.y, sc = blockIdx.z;
  const f16x2* pa = (const f16x2*)(Hb + ((size_t)b * 512 + sc * 32) * HID) + h2;
  const f16x2* pc = (const f16x2*)(C2b + ((size_t)b * 512 + sc * 32) * HID) + h2;
  float a0 = 0.f, a1 = 0.f, c0 = 0.f, c1 = 0.f;
  #pragma unroll 4
  for (int s = 0; s < 32; ++s) {
    f16x2 va = pa[(size_t)s * 512];
    f16x2 vc = pc[(size_t)s * 512];
    a0 += (float)va[0]; a1 += (float)va[1];
    c0 += (float)vc[0]; c1 += (float)vc[1];
  }
  float* oh = pH + ((size_t)sc * 8 + b) * HID;
  float* oc = pC + ((size_t)sc * 8 + b) * HID;
  oh[h2 * 2] = a0; oh[h2 * 2 + 1] = a1;
  oc[h2 * 2] = c0; oc[h2 * 2 + 1] = c1;
}

// ---------------------------------------------------------------------------
// sent[b][col] = mean_s H + b3[col] + (mean_s C2) @ w3   (exact commute).
// ---------------------------------------------------------------------------
__global__ __launch_bounds__(256) void sent_kernel(
    const float* __restrict__ pH, const float* __restrict__ pC,
    const f16* __restrict__ WT2, const float* __restrict__ b3,
    float* __restrict__ sent)
{
  __shared__ float c2m[HID];
  const int tid = threadIdx.x;
  const int b = blockIdx.x >> 2, ch = blockIdx.x & 3;
  for (int kk = tid; kk < HID; kk += 256) {
    float s = 0.f;
    #pragma unroll
    for (int sc = 0; sc < 16; ++sc) s += pC[((size_t)sc * 8 + b) * HID + kk];
    c2m[kk] = s * (1.f / 512.f);
  }
  __syncthreads();
  const int col = ch * 256 + tid;
  float hv = 0.f;
  #pragma unroll
  for (int sc = 0; sc < 16; ++sc) hv += pH[((size_t)sc * 8 + b) * HID + col];
  float acc = hv * (1.f / 512.f) + b3[col];
  const f16* wrow = WT2 + (size_t)col * HID;
  for (int k0 = 0; k0 < HID; k0 += 8) {
    f16x8 wv = *(const f16x8*)(wrow + k0);
    #pragma unroll
    for (int j = 0; j < 8; ++j) acc += c2m[k0 + j] * (float)wv[j];
  }
  sent[b * HID + col] = acc;
}

// ---------------------------------------------------------------------------
__global__ __launch_bounds__(1024) void loss_kernel(
    const float* __restrict__ sent, const int* __restrict__ y,
    float* __restrict__ out)
{
  __shared__ float red[17];
  const int tid = threadIdx.x;
  const int wid = tid >> 6, lane = tid & 63;
  float loss = 0.0f;
  for (int b = 0; b < 8; ++b) {
    const float v = sent[b * HID + tid];
    float m = v;
    #pragma unroll
    for (int o = 32; o; o >>= 1) m = fmaxf(m, __shfl_xor(m, o, 64));
    if (lane == 0) red[wid] = m;
    __syncthreads();
    if (tid < 16) {
      float mm = red[tid];
      #pragma unroll
      for (int o = 8; o; o >>= 1) mm = fmaxf(mm, __shfl_xor(mm, o, 16));
      if (tid == 0) red[16] = mm;
    }
    __syncthreads();
    const float M = red[16];
    float s = expf(v - M);
    #pragma unroll
    for (int o = 32; o; o >>= 1) s += __shfl_xor(s, o, 64);
    __syncthreads();
    if (lane == 0) red[wid] = s;
    __syncthreads();
    if (tid < 16) {
      float ss = red[tid];
      #pragma unroll
      for (int o = 8; o; o >>= 1) ss += __shfl_xor(ss, o, 16);
      if (tid == 0) red[16] = M + logf(ss);
    }
    __syncthreads();
    if (tid == 0) loss += -(sent[b * HID + y[b]] - red[16]);
    __syncthreads();
  }
  if (tid == 0) out[0] = loss * (1.0f / 8.0f);
}

// ---------------------------------------------------------------------------
extern "C" void kernel_launch(void* const* d_in, const int* in_sizes, int n_in,
                              void* d_out, int out_size, void* d_ws, size_t ws_size,
                              hipStream_t stream)
{
  const float* x    = (const float*)d_in[0];
  const int*   y    = (const int*)d_in[1];
  const float* w1   = (const float*)d_in[2];
  const float* b1   = (const float*)d_in[3];
  const float* w2   = (const float*)d_in[4];
  const float* b2   = (const float*)d_in[5];
  const float* w3   = (const float*)d_in[6];
  const float* b3   = (const float*)d_in[7];
  const float* wg1  = (const float*)d_in[8];
  const float* e1w1 = (const float*)d_in[9];
  const float* e1b1 = (const float*)d_in[10];
  const float* e1w2 = (const float*)d_in[11];
  const float* e1b2 = (const float*)d_in[12];
  const float* wg2  = (const float*)d_in[13];
  const float* e2w1 = (const float*)d_in[14];
  const float* e2b1 = (const float*)d_in[15];
  const float* e2w2 = (const float*)d_in[16];
  const float* e2b2 = (const float*)d_in[17];

  // workspace (~137 MB)
  f16* WT = (f16*)d_ws;                          // 35 x [1024][1024] f16
  f16* X0 = WT + (size_t)35 * WSZ;               // [4096][1024]
  f16* H  = X0 + (size_t)TOK * HID;              // [4097][1024] (pad row)
  f16* EA = H + (size_t)(TOK + 1) * HID;         // [4096][1024]
  f16* C1 = EA + (size_t)TOK * HID;              // [4096][1024]
  f16* M1 = C1 + (size_t)TOK * HID;              // [4097][1024] (pad row)
  f16* C2 = M1 + (size_t)(TOK + 1) * HID;        // [4096][1024]
  float* gmax  = (float*)(C2 + (size_t)TOK * HID);
  int* idx     = (int*)(gmax + TOK);
  int* rowmap  = idx + TOK;
  float* sent  = (float*)(rowmap + NEXP * CAP);
  float* pH    = sent + 8 * HID;                 // [16][8][1024]
  float* pC    = pH + 16 * 8 * HID;              // [16][8][1024]

  f16* WTe1a = WT + (size_t)3 * WSZ;
  f16* WTe1b = WT + (size_t)11 * WSZ;
  f16* WTe2a = WT + (size_t)19 * WSZ;
  f16* WTe2b = WT + (size_t)27 * WSZ;

  const int FUSED = 256 + 512;   // 256 gemm + 8 mats x 64 slab blocks

  // prep: x cast + zeros + w1/w2/w3 transposes
  prep2<<<1216, 512, 0, stream>>>(x, X0, C1, C2,
                                  H + (size_t)TOK * HID, M1 + (size_t)TOK * HID,
                                  w1, w2, w3, WT);

  // g1: H = X0 @ w1^T + b1  (+ transpose e1w1)
  gemm_fused<0><<<FUSED, 512, 0, stream>>>(X0, WT, b1, H, nullptr, nullptr,
                                           TOK, 0, 0, e1w1, WTe1a, 256);

  // ---- MoE layer 1 ----
  gate_kernel<<<512, 256, 0, stream>>>(H, wg1, idx, gmax);
  scan_kernel<<<1, 512, 0, stream>>>(idx, rowmap);
  gemm_fused<1><<<FUSED, 512, 0, stream>>>(H, WTe1a, e1b1, EA, rowmap, nullptr,
                                           CAP, WSZ, HID, e1w2, WTe1b, 256);
  gemm_fused<2><<<FUSED, 512, 0, stream>>>(EA, WTe1b, e1b2, C1, rowmap, gmax,
                                           CAP, WSZ, HID, e2w1, WTe2a, 256);

  // g4: M1 = C1 @ w2^T + b2  (+ transpose e2w2)
  gemm_fused<0><<<FUSED, 512, 0, stream>>>(C1, WT + (size_t)1 * WSZ, b2, M1,
                                           nullptr, nullptr, TOK, 0, 0,
                                           e2w2, WTe2b, 256);

  // ---- MoE layer 2 ----
  gate_kernel<<<512, 256, 0, stream>>>(M1, wg2, idx, gmax);
  scan_kernel<<<1, 512, 0, stream>>>(idx, rowmap);
  gemm_fused<1><<<256, 512, 0, stream>>>(M1, WTe2a, e2b1, EA, rowmap, nullptr,
                                         CAP, WSZ, HID, w1, WT, 256);
  gemm_fused<2><<<256, 512, 0, stream>>>(EA, WTe2b, e2b2, C2, rowmap, gmax,
                                         CAP, WSZ, HID, w1, WT, 256);

  // final: sent = mean_s(H) + mean_s(C2) @ w3 + b3  (mean commutes with w3)
  meanHC_kernel<<<dim3(2, 8, 16), 256, 0, stream>>>(H, C2, pH, pC);
  sent_kernel<<<32, 256, 0, stream>>>(pH, pC, WT + (size_t)2 * WSZ, b3, sent);
  loss_kernel<<<1, 1024, 0, stream>>>(sent, y, (float*)d_out);
}